// Round 1
// baseline (971.658 us; speedup 1.0000x reference)
//
#include <hip/hip_runtime.h>
#include <math.h>

// Problem constants (from reference)
#define BB 8
#define HH 32
#define DD 128
#define TT 64
#define PP 64
#define SELN 32
#define NSPLIT 4
#define PPS (SELN / NSPLIT)   // 8 pages per split

// ---------------------------------------------------------------------------
// Kernel 1: RoPE (NeoX) on q.  grid = B*H blocks, 64 threads.
// thread i handles the rotation pair (i, i+64).
// Double-precision trig so our qr tracks the numpy reference closely
// (page top-k selection is sensitive to score perturbation).
// ---------------------------------------------------------------------------
__global__ void rope_kernel(const float* __restrict__ q,
                            const int* __restrict__ seq_lens,
                            float* __restrict__ qr) {
    int bh = blockIdx.x;        // b*H + h
    int i  = threadIdx.x;       // 0..63
    int b  = bh >> 5;           // H = 32
    float pos = (float)(seq_lens[b] - 1);
    double invf_d = pow(10000.0, -(double)i / 64.0);   // 10000^(-2i/D)
    float ang = pos * (float)invf_d;                   // f32 like reference
    double sd, cd;
    sincos((double)ang, &sd, &cd);
    float c = (float)cd, s = (float)sd;
    const float* qp = q  + (size_t)bh * DD;
    float*       op = qr + (size_t)bh * DD;
    float x1 = qp[i], x2 = qp[i + 64];
    op[i]      = x1 * c - x2 * s;
    op[i + 64] = x2 * c + x1 * s;
}

// ---------------------------------------------------------------------------
// Kernel 2: page scores.  One block per (b, p, h); 256 threads.
// score(b,h,p) = k_scale * (1/T) * sum_{t,d} K[phys,h,t,d] * qr[b,h,d]
// Coalesced int4 loads; exact integer column sums; invalid pages -> -inf
// (no memory read).
// ---------------------------------------------------------------------------
__global__ void __launch_bounds__(256) page_score_kernel(
        const int* __restrict__ kc, const int* __restrict__ bt,
        const float* __restrict__ qr, const int* __restrict__ seq_lens,
        const float* __restrict__ k_scale, float* __restrict__ scores) {
    int blk = blockIdx.x;               // b*(P*H) + p*H + h
    int h = blk & (HH - 1);
    int p = (blk >> 5) & (PP - 1);
    int b = blk >> 11;
    int tid = threadIdx.x;

    int seq = seq_lens[b];
    int nvalid = (seq + TT - 1) >> 6;
    int sidx = (b * HH + h) * PP + p;   // scores[b][h][p]
    if (p >= nvalid) {
        if (tid == 0) scores[sidx] = -INFINITY;
        return;
    }
    int phys = bt[b * PP + p];
    const int4* K4 = (const int4*)(kc + (((size_t)phys * HH + h) << 13)); // T*D=8192

    int d0 = (tid & 31) * 4;            // fixed 4 dims per thread
    const float* qp = qr + (size_t)(b * HH + h) * DD;
    float q0 = qp[d0], q1 = qp[d0 + 1], q2 = qp[d0 + 2], q3 = qp[d0 + 3];

    int s0 = 0, s1 = 0, s2 = 0, s3 = 0;
#pragma unroll
    for (int it = 0; it < 8; ++it) {
        int4 kv = K4[tid + it * 256];   // coalesced 4 KB per iter
        s0 += kv.x; s1 += kv.y; s2 += kv.z; s3 += kv.w;
    }
    float pd = q0 * (float)s0 + q1 * (float)s1 + q2 * (float)s2 + q3 * (float)s3;
#pragma unroll
    for (int off = 32; off >= 1; off >>= 1) pd += __shfl_xor(pd, off);

    __shared__ float ls[4];
    if ((tid & 63) == 0) ls[tid >> 6] = pd;
    __syncthreads();
    if (tid == 0) {
        float tot = ls[0] + ls[1] + ls[2] + ls[3];
        scores[sidx] = tot * k_scale[0] * (1.0f / (float)TT);
    }
}

// ---------------------------------------------------------------------------
// Kernel 3: top-SEL selection per (b,h).  64 lanes; iterative argmax with
// jax.lax.top_k tie-breaking (equal values -> lower index first).
// Stores the PAGE index p (not phys id) so the attention kernel can mask.
// ---------------------------------------------------------------------------
__global__ void topk_kernel(const float* __restrict__ scores,
                            int* __restrict__ sel_p) {
    int bh = blockIdx.x;
    int lane = threadIdx.x;             // 0..63
    float s = scores[(size_t)bh * PP + lane];
    int base = bh * SELN;
    for (int it = 0; it < SELN; ++it) {
        float v = s; int idx = lane;
#pragma unroll
        for (int off = 32; off >= 1; off >>= 1) {
            float ov = __shfl_xor(v, off);
            int   oi = __shfl_xor(idx, off);
            if (ov > v || (ov == v && oi < idx)) { v = ov; idx = oi; }
        }
        if (lane == 0) sel_p[base + it] = idx;
        if (lane == idx) s = -INFINITY;
    }
}

// ---------------------------------------------------------------------------
// Kernel 4: split attention.  grid = B*H*NSPLIT, 256 threads.
// Each block: 8 pages, online softmax (m, l, acc), flash-decoding partials.
// Thread layout: tid covers dims d0=(tid&31)*4; token group g = tid>>5.
// ---------------------------------------------------------------------------
__global__ void __launch_bounds__(256) attn_split_kernel(
        const int* __restrict__ kc, const int* __restrict__ vc,
        const int* __restrict__ bt, const int* __restrict__ sel_p,
        const float* __restrict__ qr, const int* __restrict__ seq_lens,
        const float* __restrict__ k_scale, float* __restrict__ splits) {
    int blk = blockIdx.x;
    int split = blk & (NSPLIT - 1);
    int bh = blk >> 2;
    int b = bh >> 5;
    int tid = threadIdx.x;
    int lane = tid & 63;
    int g = tid >> 5;                   // token group 0..7

    int seq = seq_lens[b];
    float kssm = k_scale[0] * (1.0f / sqrtf((float)DD));

    int d0 = (tid & 31) * 4;
    const float* qp = qr + (size_t)bh * DD;
    float q0 = qp[d0] * kssm, q1 = qp[d0 + 1] * kssm,
          q2 = qp[d0 + 2] * kssm, q3 = qp[d0 + 3] * kssm;

    float m = -INFINITY, l = 0.0f;
    float a0 = 0.f, a1 = 0.f, a2 = 0.f, a3 = 0.f;

    __shared__ float plog[TT];

    for (int pp = 0; pp < PPS; ++pp) {
        int p_idx = sel_p[(size_t)bh * SELN + split * PPS + pp];
        int phys  = bt[b * PP + p_idx];
        int nt = seq - p_idx * TT;      // valid tokens in this page (>=1)
        if (nt > TT) nt = TT;
        size_t slab = ((size_t)phys * HH + (bh & 31)) << 13;

        // ---- K pass: 64 logits ----
        const int4* K4 = (const int4*)(kc + slab);
#pragma unroll
        for (int it = 0; it < 8; ++it) {
            int4 kv = K4[tid + it * 256];
            float pd = q0 * (float)kv.x + q1 * (float)kv.y +
                       q2 * (float)kv.z + q3 * (float)kv.w;
#pragma unroll
            for (int off = 16; off >= 1; off >>= 1) pd += __shfl_xor(pd, off);
            int t = g + (it << 3);
            if ((tid & 31) == 0) plog[t] = (t < nt) ? pd : -INFINITY;
        }
        __syncthreads();

        // ---- online softmax update (each wave redundantly) ----
        float lv = plog[lane];
        float pm = lv;
#pragma unroll
        for (int off = 32; off >= 1; off >>= 1) pm = fmaxf(pm, __shfl_xor(pm, off));
        float m_new = fmaxf(m, pm);            // finite: every page has >=1 token
        float scale = __expf(m - m_new);       // first page: exp(-inf)=0
        float e = __expf(lv - m_new);          // lane holds e[token=lane]
        float ssum = e;
#pragma unroll
        for (int off = 32; off >= 1; off >>= 1) ssum += __shfl_xor(ssum, off);
        l = l * scale + ssum;
        a0 *= scale; a1 *= scale; a2 *= scale; a3 *= scale;
        m = m_new;

        // ---- V pass: acc += w[t] * V ----
        const int4* V4 = (const int4*)(vc + slab);
#pragma unroll
        for (int it = 0; it < 8; ++it) {
            int4 vv = V4[tid + it * 256];
            int t = g + (it << 3);
            float wt = __shfl(e, t);           // broadcast weight of token t
            a0 += wt * (float)vv.x; a1 += wt * (float)vv.y;
            a2 += wt * (float)vv.z; a3 += wt * (float)vv.w;
        }
        __syncthreads();                       // plog reused next page
    }

    // ---- reduce acc across the 8 token-groups sharing dims ----
    __shared__ float racc[256 * 4];
    racc[tid * 4 + 0] = a0; racc[tid * 4 + 1] = a1;
    racc[tid * 4 + 2] = a2; racc[tid * 4 + 3] = a3;
    __syncthreads();
    size_t obase = (size_t)blk * (DD + 2);
    if (tid < 32) {
        float r0 = 0.f, r1 = 0.f, r2 = 0.f, r3 = 0.f;
        for (int j = tid; j < 256; j += 32) {
            r0 += racc[j * 4 + 0]; r1 += racc[j * 4 + 1];
            r2 += racc[j * 4 + 2]; r3 += racc[j * 4 + 3];
        }
        splits[obase + d0 + 0] = r0; splits[obase + d0 + 1] = r1;
        splits[obase + d0 + 2] = r2; splits[obase + d0 + 3] = r3;
    }
    if (tid == 0) { splits[obase + DD] = m; splits[obase + DD + 1] = l; }
}

// ---------------------------------------------------------------------------
// Kernel 5: combine splits.  grid = B*H, 128 threads (one per dim).
// ---------------------------------------------------------------------------
__global__ void combine_kernel(const float* __restrict__ splits,
                               const float* __restrict__ v_scale,
                               float* __restrict__ out) {
    int bh = blockIdx.x;
    int d = threadIdx.x;
    const float* sp = splits + (size_t)bh * NSPLIT * (DD + 2);
    float M = -INFINITY;
#pragma unroll
    for (int s = 0; s < NSPLIT; ++s) M = fmaxf(M, sp[s * (DD + 2) + DD]);
    float L = 0.f, val = 0.f;
#pragma unroll
    for (int s = 0; s < NSPLIT; ++s) {
        float es = __expf(sp[s * (DD + 2) + DD] - M);
        L   += sp[s * (DD + 2) + DD + 1] * es;
        val += sp[s * (DD + 2) + d] * es;
    }
    out[(size_t)bh * DD + d] = val / L * v_scale[0];
}

// ---------------------------------------------------------------------------
extern "C" void kernel_launch(void* const* d_in, const int* in_sizes, int n_in,
                              void* d_out, int out_size, void* d_ws, size_t ws_size,
                              hipStream_t stream) {
    const float* q  = (const float*)d_in[0];
    const int*   kc = (const int*)d_in[1];
    const int*   vc = (const int*)d_in[2];
    const int*   bt = (const int*)d_in[3];
    const int*   sl = (const int*)d_in[4];
    const float* ks = (const float*)d_in[5];
    const float* vs = (const float*)d_in[6];
    float* out = (float*)d_out;

    float* ws     = (float*)d_ws;
    float* qr     = ws;                 // B*H*D       = 32768 floats
    float* scores = ws + 32768;         // B*H*P       = 16384 floats
    int*   sel    = (int*)(ws + 49152); // B*H*SEL     =  8192 ints
    float* splits = ws + 57344;         // B*H*NSPLIT*(D+2) = 133120 floats

    rope_kernel<<<BB * HH, 64, 0, stream>>>(q, sl, qr);
    page_score_kernel<<<BB * PP * HH, 256, 0, stream>>>(kc, bt, qr, sl, ks, scores);
    topk_kernel<<<BB * HH, 64, 0, stream>>>(scores, sel);
    attn_split_kernel<<<BB * HH * NSPLIT, 256, 0, stream>>>(kc, vc, bt, sel, qr, sl, ks, splits);
    combine_kernel<<<BB * HH, 128, 0, stream>>>(splits, vs, out);
}